// Round 5
// baseline (189.949 us; speedup 1.0000x reference)
//
#include <hip/hip_runtime.h>
#include <hip/hip_bf16.h>
#include <stdint.h>

// Problem dims (fixed by reference)
#define HH 224
#define WW 224
#define CC 1024
#define BB 256
#define KK (HH*WW)            // 50176
#define EPSILON_F 0.001f
#define LOG2E 1.4426950408889634f
#define INVN (1.0f/50176.0f)
// clip(v,+-2000)/N == clip(v/N, +-2000/N) since 1/N > 0
#define CLAMP_V (2000.0f/50176.0f)

// K-split: 32 chunks of 7 rows. Tile: 256m x 32c, 4 waves (each 64m x 32c).
// grid = 1024 blocks = 4 blocks/CU = 16 waves/CU (VGPR cap at 112 regs).
// XCD swizzle (R1: FETCH 200MB->13.6MB): each XCD owns 4 k-chunks; all readers of
// one x-slice are co-resident on ONE XCD so x is L2-served after first touch.
// R2 POST-MORTEM: full 7x-unroll restructure regressed 2.7x -> reverted.
// R3 POST-MORTEM: fp32-direct gemm 56.6->75us (L2 thrash); cvt prepass restored.
// R4 POST-MORTEM: deleting the A-LDS round-trip cut VALU 35->25.6% and conflicts
// 4M->0.8M but time didn't move (56.6->55.8us) -> kernel is LATENCY-bound:
// 1 barrier/step with only 2 waves/SIMD resident; ds_read/L2-load latency exposed.
// R5 (this round): c-tile 64->32. Work per wave halves, resident waves double
// (2->4 blocks/CU). Chip-wide MFMA and B-gen VALU unchanged; A-reads double but
// are L2-hits inside the owning XCD. Loop structure untouched.
#define KCHUNKS 32
#define ROWS_PER_CHUNK 7
#define STEPS 49              // 7 wb * 7 rows

// 36 elems = 72 B rows: 16-row b128 bank starts (18*r)%32 all distinct -> <=2-way
#define LDS_STRIDE 36

typedef __bf16 bf16x8 __attribute__((ext_vector_type(8)));
typedef float  f32x4  __attribute__((ext_vector_type(4)));

// ---------------- prepass: x fp32 -> bf16 -------------------------------------------------
__global__ __launch_bounds__(256)
void cvt_bf16_kernel(const float* __restrict__ x, __hip_bfloat16* __restrict__ xb, int n8) {
    int i = blockIdx.x * 256 + threadIdx.x;   // one thread per 8 elements
    if (i >= n8) return;
    const float4* p = (const float4*)(x + (size_t)i * 8);
    float4 a = p[0], b = p[1];
    union { __hip_bfloat16 h[8]; uint4 u; } o;
    o.h[0] = (__hip_bfloat16)a.x; o.h[1] = (__hip_bfloat16)a.y;
    o.h[2] = (__hip_bfloat16)a.z; o.h[3] = (__hip_bfloat16)a.w;
    o.h[4] = (__hip_bfloat16)b.x; o.h[5] = (__hip_bfloat16)b.y;
    o.h[6] = (__hip_bfloat16)b.z; o.h[7] = (__hip_bfloat16)b.w;
    *(uint4*)(xb + (size_t)i * 8) = o.u;
}

// ---------------- reduce: out[m][c] = sum_z part[z][m][c] --------------------------------
__global__ __launch_bounds__(256)
void reduce_kernel(const float* __restrict__ part, float* __restrict__ out) {
    int i = blockIdx.x * 256 + threadIdx.x;          // 65536 float4 slots
    const f32x4* p = (const f32x4*)part + i;
    f32x4 s = {0.f, 0.f, 0.f, 0.f};
#pragma unroll
    for (int z = 0; z < KCHUNKS; ++z)
        s += p[(size_t)z * (BB * CC / 4)];
    ((f32x4*)out)[i] = s;
}

// ---------------- main fused curve-gen + GEMM --------------------------------------------
// NOTE: no min-waves arg in __launch_bounds__ (earlier: (256,7) spilled the accumulator).
template <bool BF16A, bool PARTIAL>
__global__ __launch_bounds__(256)
void blob_gemm_kernel(const void* __restrict__ xin,
                      const float* __restrict__ pos,
                      const float* __restrict__ sig,
                      const float* __restrict__ cwt,
                      const float* __restrict__ xs,
                      const float* __restrict__ ys,
                      float* __restrict__ dst) {
    // B tile only (A goes global->register directly)
    __shared__ __bf16 Bs[2][32 * LDS_STRIDE];    // 32 c-rows x 32 k
    __shared__ float  xrow[WW];
    __shared__ float  ycol[ROWS_PER_CHUNK];

    const int tid  = threadIdx.x;
    const int wave = tid >> 6;
    const int lane = tid & 63;

    // ---- XCD-aware swizzle (bijective on 1024): xcd = n&7 owns z in [4*xcd, 4*xcd+4) ----
    const int n  = blockIdx.x;
    const int j  = n >> 3;                             // 0..127
    const int z  = (n & 7) * 4 + (j >> 5);             // K-chunk (32)
    const int c0 = (j & 31) * 32;                      // N-tile (32)
    const int k0 = z * (ROWS_PER_CHUNK * WW);

    if (tid < WW) xrow[tid] = xs[tid];                 // x_axis
    if (tid >= WW && tid < WW + ROWS_PER_CHUNK)
        ycol[tid - WW] = ys[(z * ROWS_PER_CHUNK + (tid - WW)) * WW];  // y_axis

    // ---- per-thread curve params: one c per thread, one k-quartet ----
    const int q   = tid & 7;            // k-quartet (4 wide) within 32-wide step
    const int cr0 = tid >> 3;           // 0..31: c-row
    const int c   = c0 + cr0;
    float A2, S2, P0, P1;
    {
        float s  = sig[c];
        float w  = cwt[c];
        float s2 = s * s;
        A2 = w / (6.283185307179586f * s2 + EPSILON_F) * INVN;
        S2 = LOG2E / (2.0f * s2 + EPSILON_F);
        P0 = pos[2 * c];
        P1 = pos[2 * c + 1];
    }
    // clamp is the identity unless some lane's |A2| can exceed CLAMP_V:
    // |v| = |A2| * Ex * ey with Ex,ey in (0,1]  -> wave-uniform skip, exact.
    const bool doClamp = __any(fabsf(A2) > CLAMP_V) != 0;

    const int bs_w = cr0 * LDS_STRIDE + q * 4;

    // wave m-quadrant: wave w covers m rows [64w, 64w+64), all 32 c
    const int wm = wave * 64;
    const int fl = lane & 15;
    const int fk = (lane >> 4) * 8;
    const int br_off = fl * LDS_STRIDE + fk;

    // ---- A fragment base pointers: global, MFMA layout (row wm+fl+16mi, k fk..fk+7) ----
    const __hip_bfloat16* afb[4];
    const float* aff[4];
#pragma unroll
    for (int mi = 0; mi < 4; ++mi) {
        size_t off = (size_t)(wm + fl + mi * 16) * KK + k0 + fk;
        afb[mi] = (const __hip_bfloat16*)xin + off;
        aff[mi] = (const float*)xin + off;
    }

    f32x4 acc[4][2];
#pragma unroll
    for (int i = 0; i < 4; ++i)
#pragma unroll
        for (int jj = 0; jj < 2; ++jj) acc[i][jj] = (f32x4){0.f, 0.f, 0.f, 0.f};

    __syncthreads();   // axes ready

    // y-axis values into registers (7 broadcast LDS reads, once)
    float ycolr[ROWS_PER_CHUNK];
#pragma unroll
    for (int r = 0; r < ROWS_PER_CHUNK; ++r) ycolr[r] = ycol[r];

    // ---- step 0: A fragments direct from global; B generated into buffer 0 ----
    bf16x8 fa[4];
#pragma unroll
    for (int mi = 0; mi < 4; ++mi) {
        if (BF16A) {
            fa[mi] = *(const bf16x8*)(afb[mi]);
        } else {
            float4 f0 = *(const float4*)(aff[mi]);
            float4 f1 = *(const float4*)(aff[mi] + 4);
            bf16x8 t;
            t[0] = (__bf16)f0.x; t[1] = (__bf16)f0.y; t[2] = (__bf16)f0.z; t[3] = (__bf16)f0.w;
            t[4] = (__bf16)f1.x; t[5] = (__bf16)f1.y; t[6] = (__bf16)f1.z; t[7] = (__bf16)f1.w;
            fa[mi] = t;
        }
    }
    float Ex[4];
    {
        float4 xv = *(const float4*)(xrow + q * 4);
        float xvv[4] = {xv.x, xv.y, xv.z, xv.w};
#pragma unroll
        for (int i = 0; i < 4; ++i) {
            float dx = xvv[i] - P1;
            Ex[i] = __builtin_amdgcn_exp2f(-(dx * S2 * dx));
        }
        float dy  = ycolr[0] - P0;
        float eyA = __builtin_amdgcn_exp2f(-(dy * S2 * dy)) * A2;
        float v[4];
#pragma unroll
        for (int i = 0; i < 4; ++i) v[i] = Ex[i] * eyA;
        if (doClamp) {
#pragma unroll
            for (int i = 0; i < 4; ++i) v[i] = fminf(fmaxf(v[i], -CLAMP_V), CLAMP_V);
        }
        union { __bf16 h[4]; uint2 u; } cv;
#pragma unroll
        for (int i = 0; i < 4; ++i) cv.h[i] = (__bf16)v[i];
        *(uint2*)(&Bs[0][bs_w]) = cv.u;
    }
    __syncthreads();   // buffer 0 ready

    // ---- main loop: step s computes on Bs[s&1]; stages B(s+1) into Bs[(s&1)^1];
    //      A(s+1) prefetched global->reg during s. 1 barrier/step. ----
    int nr = 1, nwb = 0;   // (row, wb) of the step being staged (s+1)
#pragma unroll 2
    for (int s = 0; s < STEPS; ++s) {
        const int cb = s & 1;

        // 1. prefetch next A fragments (longest latency first)
        uint4  pa[4];
        float4 pf0[4], pf1[4];
        if (s < STEPS - 1) {
            const int koff = nr * WW + nwb * 32;   // wave-uniform
            if (BF16A) {
#pragma unroll
                for (int mi = 0; mi < 4; ++mi) pa[mi] = *(const uint4*)(afb[mi] + koff);
            } else {
#pragma unroll
                for (int mi = 0; mi < 4; ++mi) {
                    pf0[mi] = *(const float4*)(aff[mi] + koff);
                    pf1[mi] = *(const float4*)(aff[mi] + koff + 4);
                }
            }
        }

        // 2. B fragments from current buffer
        bf16x8 fb[2];
#pragma unroll
        for (int i = 0; i < 2; ++i)
            fb[i] = *(const bf16x8*)(&Bs[cb][br_off + i * 16 * LDS_STRIDE]);

        // 3. generate B for step s+1 into the other buffer (overlaps ds_read latency;
        //    other buffer was last read at s-1, protected by that barrier)
        if (s < STEPS - 1) {
            if (nr == 0) {   // new wb: refresh Ex (wave-uniform branch)
                float4 xv = *(const float4*)(xrow + nwb * 32 + q * 4);
                float xvv[4] = {xv.x, xv.y, xv.z, xv.w};
#pragma unroll
                for (int i = 0; i < 4; ++i) {
                    float dx = xvv[i] - P1;
                    Ex[i] = __builtin_amdgcn_exp2f(-(dx * S2 * dx));
                }
            }
            float dy  = ycolr[nr] - P0;
            float eyA = __builtin_amdgcn_exp2f(-(dy * S2 * dy)) * A2;
            float v[4];
#pragma unroll
            for (int i = 0; i < 4; ++i) v[i] = Ex[i] * eyA;
            if (doClamp) {
#pragma unroll
                for (int i = 0; i < 4; ++i) v[i] = fminf(fmaxf(v[i], -CLAMP_V), CLAMP_V);
            }
            union { __bf16 h[4]; uint2 u; } cv;
#pragma unroll
            for (int i = 0; i < 4; ++i) cv.h[i] = (__bf16)v[i];
            *(uint2*)(&Bs[cb ^ 1][bs_w]) = cv.u;
            ++nr;
            if (nr == ROWS_PER_CHUNK) { nr = 0; ++nwb; }
        }

        // 4. 8 MFMAs (fa in registers, fb from LDS)
#pragma unroll
        for (int mi = 0; mi < 4; ++mi)
#pragma unroll
            for (int ni = 0; ni < 2; ++ni)
                acc[mi][ni] = __builtin_amdgcn_mfma_f32_16x16x32_bf16(
                    fa[mi], fb[ni], acc[mi][ni], 0, 0, 0);

        // 5. commit prefetched A as next step's fragments
        if (s < STEPS - 1) {
            if (BF16A) {
#pragma unroll
                for (int mi = 0; mi < 4; ++mi) {
                    union { uint4 u; bf16x8 h; } t; t.u = pa[mi];
                    fa[mi] = t.h;
                }
            } else {
#pragma unroll
                for (int mi = 0; mi < 4; ++mi) {
                    bf16x8 t;
                    t[0] = (__bf16)pf0[mi].x; t[1] = (__bf16)pf0[mi].y;
                    t[2] = (__bf16)pf0[mi].z; t[3] = (__bf16)pf0[mi].w;
                    t[4] = (__bf16)pf1[mi].x; t[5] = (__bf16)pf1[mi].y;
                    t[6] = (__bf16)pf1[mi].z; t[7] = (__bf16)pf1[mi].w;
                    fa[mi] = t;
                }
            }
        }
        __syncthreads();
    }

    // ---- epilogue: C/D layout col=lane&15, row=(lane>>4)*4+reg ----
    const int orow = (lane >> 4) * 4;
    float* base = PARTIAL ? (dst + (size_t)z * BB * CC) : dst;
#pragma unroll
    for (int mi = 0; mi < 4; ++mi) {
        int m = wm + mi * 16 + orow;
#pragma unroll
        for (int ni = 0; ni < 2; ++ni) {
            int cc = c0 + ni * 16 + fl;
#pragma unroll
            for (int v = 0; v < 4; ++v) {
                if (PARTIAL)
                    base[(size_t)(m + v) * CC + cc] = acc[mi][ni][v];
                else
                    atomicAdd(base + (size_t)(m + v) * CC + cc, acc[mi][ni][v]);
            }
        }
    }
}

extern "C" void kernel_launch(void* const* d_in, const int* in_sizes, int n_in,
                              void* d_out, int out_size, void* d_ws, size_t ws_size,
                              hipStream_t stream) {
    const float* x   = (const float*)d_in[0];
    const float* pos = (const float*)d_in[1];
    const float* sg  = (const float*)d_in[2];
    const float* cw  = (const float*)d_in[3];
    const float* xs  = (const float*)d_in[4];
    const float* ys  = (const float*)d_in[5];
    float* out = (float*)d_out;

    dim3 grid(32 * KCHUNKS);       // 1024 blocks (flattened, XCD-swizzled in-kernel)
    const size_t nx   = (size_t)BB * KK;
    const size_t XB   = nx * sizeof(__hip_bfloat16);            // 25.7 MB
    const size_t PART = (size_t)KCHUNKS * BB * CC * 4;          // 33.6 MB
    const int n8 = (int)(nx / 8);

    if (ws_size >= XB + PART) {
        __hip_bfloat16* xb = (__hip_bfloat16*)d_ws;
        float* part = (float*)((char*)d_ws + XB);
        cvt_bf16_kernel<<<(n8 + 255) / 256, 256, 0, stream>>>(x, xb, n8);
        blob_gemm_kernel<true, true><<<grid, 256, 0, stream>>>(xb, pos, sg, cw, xs, ys, part);
        reduce_kernel<<<BB * CC / 4 / 256, 256, 0, stream>>>(part, out);
    } else if (ws_size >= PART) {
        float* part = (float*)d_ws;
        blob_gemm_kernel<false, true><<<grid, 256, 0, stream>>>(x, pos, sg, cw, xs, ys, part);
        reduce_kernel<<<BB * CC / 4 / 256, 256, 0, stream>>>(part, out);
    } else if (ws_size >= XB) {
        __hip_bfloat16* xb = (__hip_bfloat16*)d_ws;
        hipMemsetAsync(out, 0, (size_t)BB * CC * sizeof(float), stream);
        cvt_bf16_kernel<<<(n8 + 255) / 256, 256, 0, stream>>>(x, xb, n8);
        blob_gemm_kernel<true, false><<<grid, 256, 0, stream>>>(xb, pos, sg, cw, xs, ys, out);
    } else {
        hipMemsetAsync(out, 0, (size_t)BB * CC * sizeof(float), stream);
        blob_gemm_kernel<false, false><<<grid, 256, 0, stream>>>(x, pos, sg, cw, xs, ys, out);
    }
}

// Round 7
// 173.561 us; speedup vs baseline: 1.0944x; 1.0944x over previous
//
#include <hip/hip_runtime.h>
#include <hip/hip_bf16.h>
#include <stdint.h>

// Problem dims (fixed by reference)
#define HH 224
#define WW 224
#define CC 1024
#define BB 256
#define KK (HH*WW)            // 50176
#define EPSILON_F 0.001f
#define LOG2E 1.4426950408889634f
#define INVN (1.0f/50176.0f)
// clip(v,+-2000)/N == clip(v/N, +-2000/N) since 1/N > 0
#define CLAMP_V (2000.0f/50176.0f)

// K-split: 32 chunks of 7 rows. Tile: 256m x 64c, 4 waves (each 64m x 64c).
// grid = 512 blocks = 2 blocks/CU (R4 geometry, known-good 55.8us).
// XCD swizzle (R1: FETCH 200MB->13.6MB): each XCD owns 4 k-chunks x 16 c-tiles.
// R2 POST-MORTEM: full 7x-unroll restructure regressed 2.7x -> reverted.
// R3 POST-MORTEM: fp32-direct gemm 56.6->75us (L2 thrash); cvt prepass restored.
// R4 POST-MORTEM: A-LDS deletion cut VALU+conflicts but time flat -> latency-bound.
// R5 POST-MORTEM: halving work/step at 2x blocks REGRESSED 55.8->101.4us: cycles
// per block-step ~constant (~1300cy) regardless of inner work -> fixed barrier-step
// latency cost dominates. Lever = fewer, fatter barrier rounds.
// R6 POST-MORTEM: paired-step kernel FAILED correctness (absmax 0.12): commit(pa->fa)
// sat at round TOP, clobbering the current round's A before its MFMAs ran (round r
// computed A(2r+2)*B(2r)). Schedule bug, not concept bug.
// R7 (this round): same pairing, fixed invariant. Round r: fa=A(2r,2r+1) ready,
// pa=A(2r+2,2r+3) in flight. Body: fb ds_reads -> stageB(2r+2,2r+3) -> 32 MFMAs
// (consume fa) -> commit pa->fa (vmcnt, full round of cover) -> issue pa(2r+4,2r+5)
// -> ONE barrier. 24 rounds + tail vs 49 barrier-steps.
#define KCHUNKS 32
#define ROWS_PER_CHUNK 7
#define STEPS 49              // 7 wb * 7 rows = 24 rounds * 2 + 1 tail

// 36 elems = 72 B rows: 16-row b128 bank starts (18*r)%32 all distinct -> <=2-way
#define LDS_STRIDE 36
#define TILE_E (64 * LDS_STRIDE)     // 2304 elems per B buffer
#define PAIR_E (2 * TILE_E)          // 4608: read-pair <-> write-pair XOR toggle

typedef __bf16 bf16x8 __attribute__((ext_vector_type(8)));
typedef float  f32x4  __attribute__((ext_vector_type(4)));

// ---------------- prepass: x fp32 -> bf16 -------------------------------------------------
__global__ __launch_bounds__(256)
void cvt_bf16_kernel(const float* __restrict__ x, __hip_bfloat16* __restrict__ xb, int n8) {
    int i = blockIdx.x * 256 + threadIdx.x;   // one thread per 8 elements
    if (i >= n8) return;
    const float4* p = (const float4*)(x + (size_t)i * 8);
    float4 a = p[0], b = p[1];
    union { __hip_bfloat16 h[8]; uint4 u; } o;
    o.h[0] = (__hip_bfloat16)a.x; o.h[1] = (__hip_bfloat16)a.y;
    o.h[2] = (__hip_bfloat16)a.z; o.h[3] = (__hip_bfloat16)a.w;
    o.h[4] = (__hip_bfloat16)b.x; o.h[5] = (__hip_bfloat16)b.y;
    o.h[6] = (__hip_bfloat16)b.z; o.h[7] = (__hip_bfloat16)b.w;
    *(uint4*)(xb + (size_t)i * 8) = o.u;
}

// ---------------- reduce: out[m][c] = sum_z part[z][m][c] --------------------------------
__global__ __launch_bounds__(256)
void reduce_kernel(const float* __restrict__ part, float* __restrict__ out) {
    int i = blockIdx.x * 256 + threadIdx.x;          // 65536 float4 slots
    const f32x4* p = (const f32x4*)part + i;
    f32x4 s = {0.f, 0.f, 0.f, 0.f};
#pragma unroll
    for (int z = 0; z < KCHUNKS; ++z)
        s += p[(size_t)z * (BB * CC / 4)];
    ((f32x4*)out)[i] = s;
}

// ---------------- main fused curve-gen + GEMM --------------------------------------------
// NOTE: no min-waves arg in __launch_bounds__ (earlier: (256,7) spilled the accumulator).
template <bool BF16A, bool PARTIAL>
__global__ __launch_bounds__(256)
void blob_gemm_kernel(const void* __restrict__ xin,
                      const float* __restrict__ pos,
                      const float* __restrict__ sig,
                      const float* __restrict__ cwt,
                      const float* __restrict__ xs,
                      const float* __restrict__ ys,
                      float* __restrict__ dst) {
    // 4 B buffers (quad-buffer: compute pair / stage pair). A goes global->register.
    __shared__ __bf16 Bs[4 * TILE_E];            // 18 KB
    __shared__ float  xrow[WW];
    __shared__ float  ycol[ROWS_PER_CHUNK];

    const int tid  = threadIdx.x;
    const int wave = tid >> 6;
    const int lane = tid & 63;

    // ---- XCD-aware swizzle (bijective on 512): xcd = n&7 owns z in [4*xcd, 4*xcd+4) ----
    const int n  = blockIdx.x;
    const int j  = n >> 3;
    const int z  = (n & 7) * 4 + (j >> 4);             // K-chunk (32)
    const int c0 = (j & 15) * 64;                      // N-tile (16)
    const int k0 = z * (ROWS_PER_CHUNK * WW);

    if (tid < WW) xrow[tid] = xs[tid];                 // x_axis
    if (tid >= WW && tid < WW + ROWS_PER_CHUNK)
        ycol[tid - WW] = ys[(z * ROWS_PER_CHUNK + (tid - WW)) * WW];  // y_axis

    // ---- per-thread curve params: one c per thread, one k-octet ----
    const int q   = tid & 3;            // k-octet within 32-wide step
    const int cr0 = tid >> 2;           // 0..63: c-row
    const int c   = c0 + cr0;
    float A2, S2, P0, P1;
    {
        float s  = sig[c];
        float w  = cwt[c];
        float s2 = s * s;
        A2 = w / (6.283185307179586f * s2 + EPSILON_F) * INVN;
        S2 = LOG2E / (2.0f * s2 + EPSILON_F);
        P0 = pos[2 * c];
        P1 = pos[2 * c + 1];
    }
    // clamp is the identity unless some lane's |A2| can exceed CLAMP_V:
    // |v| = |A2| * Ex * ey with Ex,ey in (0,1]  -> wave-uniform skip, exact.
    const bool doClamp = __any(fabsf(A2) > CLAMP_V) != 0;

    const int bs_w = cr0 * LDS_STRIDE + q * 8;

    // wave m-quadrant: wave w covers m rows [64w, 64w+64), all 64 c
    const int wm = wave * 64;
    const int fl = lane & 15;
    const int fk = (lane >> 4) * 8;
    const int br_off = fl * LDS_STRIDE + fk;

    // ---- A fragment base pointers: global, MFMA layout (row wm+fl+16mi, k fk..fk+7) ----
    const __hip_bfloat16* afb[4];
    const float* aff[4];
#pragma unroll
    for (int mi = 0; mi < 4; ++mi) {
        size_t off = (size_t)(wm + fl + mi * 16) * KK + k0 + fk;
        afb[mi] = (const __hip_bfloat16*)xin + off;
        aff[mi] = (const float*)xin + off;
    }

    f32x4 acc[4][4];
#pragma unroll
    for (int i = 0; i < 4; ++i)
#pragma unroll
        for (int jj = 0; jj < 4; ++jj) acc[i][jj] = (f32x4){0.f, 0.f, 0.f, 0.f};

    __syncthreads();   // axes ready

    // y-axis values into registers (7 broadcast LDS reads, once)
    float ycolr[ROWS_PER_CHUNK];
#pragma unroll
    for (int r = 0; r < ROWS_PER_CHUNK; ++r) ycolr[r] = ycol[r];

    // ---- B staging helper: generate step (row, wb) into Bs[wrElem..] ----
    float Ex[8];
    auto stageB = [&](int row, int wb, int wrElem) {
        if (row == 0) {   // new wb: refresh Ex (wave-uniform)
            float4 xv0 = *(const float4*)(xrow + wb * 32 + q * 8);
            float4 xv1 = *(const float4*)(xrow + wb * 32 + q * 8 + 4);
            float xv[8] = {xv0.x, xv0.y, xv0.z, xv0.w, xv1.x, xv1.y, xv1.z, xv1.w};
#pragma unroll
            for (int i = 0; i < 8; ++i) {
                float dx = xv[i] - P1;
                Ex[i] = __builtin_amdgcn_exp2f(-(dx * S2 * dx));
            }
        }
        float dy  = ycolr[row] - P0;
        float eyA = __builtin_amdgcn_exp2f(-(dy * S2 * dy)) * A2;
        float v[8];
#pragma unroll
        for (int i = 0; i < 8; ++i) v[i] = Ex[i] * eyA;
        if (doClamp) {
#pragma unroll
            for (int i = 0; i < 8; ++i) v[i] = fminf(fmaxf(v[i], -CLAMP_V), CLAMP_V);
        }
        union { __bf16 h[8]; uint4 u; } cv;
#pragma unroll
        for (int i = 0; i < 8; ++i) cv.h[i] = (__bf16)v[i];
        *(uint4*)(&Bs[wrElem + bs_w]) = cv.u;
    };

    auto loadA = [&](int koff, bf16x8* dstFrag) {
#pragma unroll
        for (int mi = 0; mi < 4; ++mi) {
            if (BF16A) {
                dstFrag[mi] = *(const bf16x8*)(afb[mi] + koff);
            } else {
                float4 f0 = *(const float4*)(aff[mi] + koff);
                float4 f1 = *(const float4*)(aff[mi] + koff + 4);
                bf16x8 t;
                t[0] = (__bf16)f0.x; t[1] = (__bf16)f0.y; t[2] = (__bf16)f0.z; t[3] = (__bf16)f0.w;
                t[4] = (__bf16)f1.x; t[5] = (__bf16)f1.y; t[6] = (__bf16)f1.z; t[7] = (__bf16)f1.w;
                dstFrag[mi] = t;
            }
        }
    };

    // prefetch registers (steps 2 ahead)
    uint4  pa0[4], pa1[4];
    float4 pf00[4], pf01[4], pf10[4], pf11[4];

    auto issue0 = [&](int koff) {
        if (BF16A) {
#pragma unroll
            for (int mi = 0; mi < 4; ++mi) pa0[mi] = *(const uint4*)(afb[mi] + koff);
        } else {
#pragma unroll
            for (int mi = 0; mi < 4; ++mi) {
                pf00[mi] = *(const float4*)(aff[mi] + koff);
                pf01[mi] = *(const float4*)(aff[mi] + koff + 4);
            }
        }
    };
    auto issue1 = [&](int koff) {
        if (BF16A) {
#pragma unroll
            for (int mi = 0; mi < 4; ++mi) pa1[mi] = *(const uint4*)(afb[mi] + koff);
        } else {
#pragma unroll
            for (int mi = 0; mi < 4; ++mi) {
                pf10[mi] = *(const float4*)(aff[mi] + koff);
                pf11[mi] = *(const float4*)(aff[mi] + koff + 4);
            }
        }
    };
    auto commit0 = [&](bf16x8* dstFrag) {
        if (BF16A) {
#pragma unroll
            for (int mi = 0; mi < 4; ++mi) {
                union { uint4 u; bf16x8 h; } t; t.u = pa0[mi];
                dstFrag[mi] = t.h;
            }
        } else {
#pragma unroll
            for (int mi = 0; mi < 4; ++mi) {
                bf16x8 t;
                t[0] = (__bf16)pf00[mi].x; t[1] = (__bf16)pf00[mi].y;
                t[2] = (__bf16)pf00[mi].z; t[3] = (__bf16)pf00[mi].w;
                t[4] = (__bf16)pf01[mi].x; t[5] = (__bf16)pf01[mi].y;
                t[6] = (__bf16)pf01[mi].z; t[7] = (__bf16)pf01[mi].w;
                dstFrag[mi] = t;
            }
        }
    };
    auto commit1 = [&](bf16x8* dstFrag) {
        if (BF16A) {
#pragma unroll
            for (int mi = 0; mi < 4; ++mi) {
                union { uint4 u; bf16x8 h; } t; t.u = pa1[mi];
                dstFrag[mi] = t.h;
            }
        } else {
#pragma unroll
            for (int mi = 0; mi < 4; ++mi) {
                bf16x8 t;
                t[0] = (__bf16)pf10[mi].x; t[1] = (__bf16)pf10[mi].y;
                t[2] = (__bf16)pf10[mi].z; t[3] = (__bf16)pf10[mi].w;
                t[4] = (__bf16)pf11[mi].x; t[5] = (__bf16)pf11[mi].y;
                t[6] = (__bf16)pf11[mi].z; t[7] = (__bf16)pf11[mi].w;
                dstFrag[mi] = t;
            }
        }
    };

    // ---- prologue: A for steps 0..3; B for steps 0,1 into pair 0 ----
    bf16x8 fa0[4], fa1[4];
    loadA(0, fa0);            // step 0 (row0,wb0)
    loadA(WW, fa1);           // step 1 (row1,wb0)
    issue0(2 * WW);           // step 2 in flight
    issue1(3 * WW);           // step 3 in flight
    stageB(0, 0, 0);
    stageB(1, 0, TILE_E);
    __syncthreads();          // pair 0 ready

    // ---- main loop: 24 rounds x 2 steps, 1 barrier/round ----
    // entry invariant: fa = A(2r,2r+1) ready; pa = A(2r+2,2r+3) in flight;
    // (nr,nwb) = (row,wb) of step 2r+2.
    int nr = 2, nwb = 0;
    int rdE = 0;
#pragma unroll 1
    for (int r = 0; r < 24; ++r) {
        // 1. B fragments for steps 2r, 2r+1 (issue ds_reads early)
        bf16x8 fb0[4], fb1[4];
#pragma unroll
        for (int i = 0; i < 4; ++i) {
            fb0[i] = *(const bf16x8*)(&Bs[rdE + br_off + i * 16 * LDS_STRIDE]);
            fb1[i] = *(const bf16x8*)(&Bs[rdE + TILE_E + br_off + i * 16 * LDS_STRIDE]);
        }

        // stage coords: t0 = step 2r+2, t1 = step 2r+3
        const int t0r = nr, t0b = nwb;
        int t1r = t0r + 1, t1b = t0b;
        if (t1r == ROWS_PER_CHUNK) { t1r = 0; ++t1b; }
        // advance counters to step 2r+4 (= next round's t0, = this round's issue u0)
        nr = t1r + 1; nwb = t1b;
        if (nr == ROWS_PER_CHUNK) { nr = 0; ++nwb; }
        int u1r = nr + 1, u1b = nwb;
        if (u1r == ROWS_PER_CHUNK) { u1r = 0; ++u1b; }

        // 2. B-gen for steps 2r+2, 2r+3 into write pair (VALU; overlaps ds_read latency)
        const int wrE = rdE ^ PAIR_E;
        stageB(t0r, t0b, wrE);                                  // valid: 2r+2 <= 48 always
        if (r < 23) stageB(t1r, t1b, wrE + TILE_E);             // 2r+3 <= 48 iff r <= 22

        // 3. 32 MFMAs consuming THIS round's fa (fa untouched until after this)
#pragma unroll
        for (int mi = 0; mi < 4; ++mi)
#pragma unroll
            for (int ni = 0; ni < 4; ++ni)
                acc[mi][ni] = __builtin_amdgcn_mfma_f32_16x16x32_bf16(
                    fa0[mi], fb0[ni], acc[mi][ni], 0, 0, 0);
#pragma unroll
        for (int mi = 0; mi < 4; ++mi)
#pragma unroll
            for (int ni = 0; ni < 4; ++ni)
                acc[mi][ni] = __builtin_amdgcn_mfma_f32_16x16x32_bf16(
                    fa1[mi], fb1[ni], acc[mi][ni], 0, 0, 0);

        // 4. commit in-flight A (steps 2r+2, 2r+3); vmcnt wait had a full round of cover
        commit0(fa0);
        commit1(fa1);   // at r=23 this is stale (unused by tail) -- harmless

        // 5. issue next A loads: u0 = step 2r+4 (r<=22), u1 = step 2r+5 (r<=21)
        if (r <= 22) issue0(nr * WW + nwb * 32);
        if (r <= 21) issue1(u1r * WW + u1b * 32);

        __syncthreads();
        rdE ^= PAIR_E;
    }

    // ---- tail: step 48. rdE==0; B48 staged at r=23 into wrE=0 tile 0; fa0=A48 ----
    {
        bf16x8 fbL[4];
#pragma unroll
        for (int i = 0; i < 4; ++i)
            fbL[i] = *(const bf16x8*)(&Bs[rdE + br_off + i * 16 * LDS_STRIDE]);
#pragma unroll
        for (int mi = 0; mi < 4; ++mi)
#pragma unroll
            for (int ni = 0; ni < 4; ++ni)
                acc[mi][ni] = __builtin_amdgcn_mfma_f32_16x16x32_bf16(
                    fa0[mi], fbL[ni], acc[mi][ni], 0, 0, 0);
    }

    // ---- epilogue: C/D layout col=lane&15, row=(lane>>4)*4+reg ----
    const int orow = (lane >> 4) * 4;
    float* base = PARTIAL ? (dst + (size_t)z * BB * CC) : dst;
#pragma unroll
    for (int mi = 0; mi < 4; ++mi) {
        int m = wm + mi * 16 + orow;
#pragma unroll
        for (int ni = 0; ni < 4; ++ni) {
            int cc = c0 + ni * 16 + fl;
#pragma unroll
            for (int v = 0; v < 4; ++v) {
                if (PARTIAL)
                    base[(size_t)(m + v) * CC + cc] = acc[mi][ni][v];
                else
                    atomicAdd(base + (size_t)(m + v) * CC + cc, acc[mi][ni][v]);
            }
        }
    }
}

extern "C" void kernel_launch(void* const* d_in, const int* in_sizes, int n_in,
                              void* d_out, int out_size, void* d_ws, size_t ws_size,
                              hipStream_t stream) {
    const float* x   = (const float*)d_in[0];
    const float* pos = (const float*)d_in[1];
    const float* sg  = (const float*)d_in[2];
    const float* cw  = (const float*)d_in[3];
    const float* xs  = (const float*)d_in[4];
    const float* ys  = (const float*)d_in[5];
    float* out = (float*)d_out;

    dim3 grid(16 * KCHUNKS);       // 512 blocks (flattened, XCD-swizzled in-kernel)
    const size_t nx   = (size_t)BB * KK;
    const size_t XB   = nx * sizeof(__hip_bfloat16);            // 25.7 MB
    const size_t PART = (size_t)KCHUNKS * BB * CC * 4;          // 33.6 MB
    const int n8 = (int)(nx / 8);

    if (ws_size >= XB + PART) {
        __hip_bfloat16* xb = (__hip_bfloat16*)d_ws;
        float* part = (float*)((char*)d_ws + XB);
        cvt_bf16_kernel<<<(n8 + 255) / 256, 256, 0, stream>>>(x, xb, n8);
        blob_gemm_kernel<true, true><<<grid, 256, 0, stream>>>(xb, pos, sg, cw, xs, ys, part);
        reduce_kernel<<<BB * CC / 4 / 256, 256, 0, stream>>>(part, out);
    } else if (ws_size >= PART) {
        float* part = (float*)d_ws;
        blob_gemm_kernel<false, true><<<grid, 256, 0, stream>>>(x, pos, sg, cw, xs, ys, part);
        reduce_kernel<<<BB * CC / 4 / 256, 256, 0, stream>>>(part, out);
    } else if (ws_size >= XB) {
        __hip_bfloat16* xb = (__hip_bfloat16*)d_ws;
        hipMemsetAsync(out, 0, (size_t)BB * CC * sizeof(float), stream);
        cvt_bf16_kernel<<<(n8 + 255) / 256, 256, 0, stream>>>(x, xb, n8);
        blob_gemm_kernel<true, false><<<grid, 256, 0, stream>>>(xb, pos, sg, cw, xs, ys, out);
    } else {
        hipMemsetAsync(out, 0, (size_t)BB * CC * sizeof(float), stream);
        blob_gemm_kernel<false, false><<<grid, 256, 0, stream>>>(x, pos, sg, cw, xs, ys, out);
    }
}

// Round 8
// 166.212 us; speedup vs baseline: 1.1428x; 1.0442x over previous
//
#include <hip/hip_runtime.h>
#include <hip/hip_bf16.h>
#include <stdint.h>

// Problem dims (fixed by reference)
#define HH 224
#define WW 224
#define CC 1024
#define BB 256
#define KK (HH*WW)            // 50176
#define EPSILON_F 0.001f
#define LOG2E 1.4426950408889634f
#define INVN (1.0f/50176.0f)
// clip(v,+-2000)/N == clip(v/N, +-2000/N) since 1/N > 0
#define CLAMP_V (2000.0f/50176.0f)

// K-split: 32 chunks of 7 rows. Tile: 256m x 64c, 4 waves (each 64m x 64c).
// grid = 512 blocks = 2 blocks/CU. XCD swizzle (R1): each XCD owns 4 k-chunks.
// R2: unroll restructure -2.7x -> reverted. R3: fp32-direct L2-thrash -> cvt kept.
// R4: A-LDS deletion; VALU/conflicts down, time flat -> latency-bound. 55.8us.
// R5: half-tile 2x-blocks regressed -> per-barrier-step cost ~fixed (~1300cy).
// R6: paired rounds, commit-at-top clobbered fa -> WRONG RESULTS.
// R7: paired rounds fixed -> PASSED but 83.5us: A-loads were issued immediately
// before the barrier; compiler drains vmcnt(0) at every s_barrier -> every round
// ate a full uncovered load latency. Busy time unchanged; all regression = stall.
// R8 (this round): same paired schedule, ISSUE MOVED TO ROUND TOP. Invariant:
// pa = A(2r,2r+1) complete at entry (forced by prev barrier drain) -> commit free;
// issue pa = A(2r+2,2r+3) right after, covered by stageB x2 + 32 MFMAs before the
// drain. 24 rounds + tail, 25 barriers vs R4's 49.
#define KCHUNKS 32
#define ROWS_PER_CHUNK 7
#define STEPS 49              // 7 wb * 7 rows = 24 rounds * 2 + 1 tail

// 36 elems = 72 B rows: 16-row b128 bank starts (18*r)%32 all distinct -> <=2-way
#define LDS_STRIDE 36
#define TILE_E (64 * LDS_STRIDE)     // 2304 elems per B buffer
#define PAIR_E (2 * TILE_E)          // 4608: read-pair <-> write-pair XOR toggle

typedef __bf16 bf16x8 __attribute__((ext_vector_type(8)));
typedef float  f32x4  __attribute__((ext_vector_type(4)));

// ---------------- prepass: x fp32 -> bf16 -------------------------------------------------
__global__ __launch_bounds__(256)
void cvt_bf16_kernel(const float* __restrict__ x, __hip_bfloat16* __restrict__ xb, int n8) {
    int i = blockIdx.x * 256 + threadIdx.x;   // one thread per 8 elements
    if (i >= n8) return;
    const float4* p = (const float4*)(x + (size_t)i * 8);
    float4 a = p[0], b = p[1];
    union { __hip_bfloat16 h[8]; uint4 u; } o;
    o.h[0] = (__hip_bfloat16)a.x; o.h[1] = (__hip_bfloat16)a.y;
    o.h[2] = (__hip_bfloat16)a.z; o.h[3] = (__hip_bfloat16)a.w;
    o.h[4] = (__hip_bfloat16)b.x; o.h[5] = (__hip_bfloat16)b.y;
    o.h[6] = (__hip_bfloat16)b.z; o.h[7] = (__hip_bfloat16)b.w;
    *(uint4*)(xb + (size_t)i * 8) = o.u;
}

// ---------------- reduce: out[m][c] = sum_z part[z][m][c] --------------------------------
__global__ __launch_bounds__(256)
void reduce_kernel(const float* __restrict__ part, float* __restrict__ out) {
    int i = blockIdx.x * 256 + threadIdx.x;          // 65536 float4 slots
    const f32x4* p = (const f32x4*)part + i;
    f32x4 s = {0.f, 0.f, 0.f, 0.f};
#pragma unroll
    for (int z = 0; z < KCHUNKS; ++z)
        s += p[(size_t)z * (BB * CC / 4)];
    ((f32x4*)out)[i] = s;
}

// ---------------- main fused curve-gen + GEMM --------------------------------------------
// NOTE: no min-waves arg in __launch_bounds__ (earlier: (256,7) spilled the accumulator).
template <bool BF16A, bool PARTIAL>
__global__ __launch_bounds__(256)
void blob_gemm_kernel(const void* __restrict__ xin,
                      const float* __restrict__ pos,
                      const float* __restrict__ sig,
                      const float* __restrict__ cwt,
                      const float* __restrict__ xs,
                      const float* __restrict__ ys,
                      float* __restrict__ dst) {
    // 4 B buffers (quad-buffer: compute pair / stage pair). A goes global->register.
    __shared__ __bf16 Bs[4 * TILE_E];            // 18 KB
    __shared__ float  xrow[WW];
    __shared__ float  ycol[ROWS_PER_CHUNK];

    const int tid  = threadIdx.x;
    const int wave = tid >> 6;
    const int lane = tid & 63;

    // ---- XCD-aware swizzle (bijective on 512): xcd = n&7 owns z in [4*xcd, 4*xcd+4) ----
    const int n  = blockIdx.x;
    const int j  = n >> 3;
    const int z  = (n & 7) * 4 + (j >> 4);             // K-chunk (32)
    const int c0 = (j & 15) * 64;                      // N-tile (16)
    const int k0 = z * (ROWS_PER_CHUNK * WW);

    if (tid < WW) xrow[tid] = xs[tid];                 // x_axis
    if (tid >= WW && tid < WW + ROWS_PER_CHUNK)
        ycol[tid - WW] = ys[(z * ROWS_PER_CHUNK + (tid - WW)) * WW];  // y_axis

    // ---- per-thread curve params: one c per thread, one k-octet ----
    const int q   = tid & 3;            // k-octet within 32-wide step
    const int cr0 = tid >> 2;           // 0..63: c-row
    const int c   = c0 + cr0;
    float A2, S2, P0, P1;
    {
        float s  = sig[c];
        float w  = cwt[c];
        float s2 = s * s;
        A2 = w / (6.283185307179586f * s2 + EPSILON_F) * INVN;
        S2 = LOG2E / (2.0f * s2 + EPSILON_F);
        P0 = pos[2 * c];
        P1 = pos[2 * c + 1];
    }
    // clamp is the identity unless some lane's |A2| can exceed CLAMP_V:
    // |v| = |A2| * Ex * ey with Ex,ey in (0,1]  -> wave-uniform skip, exact.
    const bool doClamp = __any(fabsf(A2) > CLAMP_V) != 0;

    const int bs_w = cr0 * LDS_STRIDE + q * 8;

    // wave m-quadrant: wave w covers m rows [64w, 64w+64), all 64 c
    const int wm = wave * 64;
    const int fl = lane & 15;
    const int fk = (lane >> 4) * 8;
    const int br_off = fl * LDS_STRIDE + fk;

    // ---- A fragment base pointers: global, MFMA layout (row wm+fl+16mi, k fk..fk+7) ----
    const __hip_bfloat16* afb[4];
    const float* aff[4];
#pragma unroll
    for (int mi = 0; mi < 4; ++mi) {
        size_t off = (size_t)(wm + fl + mi * 16) * KK + k0 + fk;
        afb[mi] = (const __hip_bfloat16*)xin + off;
        aff[mi] = (const float*)xin + off;
    }

    f32x4 acc[4][4];
#pragma unroll
    for (int i = 0; i < 4; ++i)
#pragma unroll
        for (int jj = 0; jj < 4; ++jj) acc[i][jj] = (f32x4){0.f, 0.f, 0.f, 0.f};

    __syncthreads();   // axes ready

    // y-axis values into registers (7 broadcast LDS reads, once)
    float ycolr[ROWS_PER_CHUNK];
#pragma unroll
    for (int r = 0; r < ROWS_PER_CHUNK; ++r) ycolr[r] = ycol[r];

    // ---- B staging helper: generate step (row, wb) into Bs[wrElem..] ----
    float Ex[8];
    auto stageB = [&](int row, int wb, int wrElem) {
        if (row == 0) {   // new wb: refresh Ex (wave-uniform)
            float4 xv0 = *(const float4*)(xrow + wb * 32 + q * 8);
            float4 xv1 = *(const float4*)(xrow + wb * 32 + q * 8 + 4);
            float xv[8] = {xv0.x, xv0.y, xv0.z, xv0.w, xv1.x, xv1.y, xv1.z, xv1.w};
#pragma unroll
            for (int i = 0; i < 8; ++i) {
                float dx = xv[i] - P1;
                Ex[i] = __builtin_amdgcn_exp2f(-(dx * S2 * dx));
            }
        }
        float dy  = ycolr[row] - P0;
        float eyA = __builtin_amdgcn_exp2f(-(dy * S2 * dy)) * A2;
        float v[8];
#pragma unroll
        for (int i = 0; i < 8; ++i) v[i] = Ex[i] * eyA;
        if (doClamp) {
#pragma unroll
            for (int i = 0; i < 8; ++i) v[i] = fminf(fmaxf(v[i], -CLAMP_V), CLAMP_V);
        }
        union { __bf16 h[8]; uint4 u; } cv;
#pragma unroll
        for (int i = 0; i < 8; ++i) cv.h[i] = (__bf16)v[i];
        *(uint4*)(&Bs[wrElem + bs_w]) = cv.u;
    };

    // prefetch registers: pa = A for the CURRENT round (completed by prev barrier drain)
    uint4  pa0[4], pa1[4];
    float4 pf00[4], pf01[4], pf10[4], pf11[4];

    auto issue0 = [&](int koff) {
        if (BF16A) {
#pragma unroll
            for (int mi = 0; mi < 4; ++mi) pa0[mi] = *(const uint4*)(afb[mi] + koff);
        } else {
#pragma unroll
            for (int mi = 0; mi < 4; ++mi) {
                pf00[mi] = *(const float4*)(aff[mi] + koff);
                pf01[mi] = *(const float4*)(aff[mi] + koff + 4);
            }
        }
    };
    auto issue1 = [&](int koff) {
        if (BF16A) {
#pragma unroll
            for (int mi = 0; mi < 4; ++mi) pa1[mi] = *(const uint4*)(afb[mi] + koff);
        } else {
#pragma unroll
            for (int mi = 0; mi < 4; ++mi) {
                pf10[mi] = *(const float4*)(aff[mi] + koff);
                pf11[mi] = *(const float4*)(aff[mi] + koff + 4);
            }
        }
    };
    auto commit0 = [&](bf16x8* dstFrag) {
        if (BF16A) {
#pragma unroll
            for (int mi = 0; mi < 4; ++mi) {
                union { uint4 u; bf16x8 h; } t; t.u = pa0[mi];
                dstFrag[mi] = t.h;
            }
        } else {
#pragma unroll
            for (int mi = 0; mi < 4; ++mi) {
                bf16x8 t;
                t[0] = (__bf16)pf00[mi].x; t[1] = (__bf16)pf00[mi].y;
                t[2] = (__bf16)pf00[mi].z; t[3] = (__bf16)pf00[mi].w;
                t[4] = (__bf16)pf01[mi].x; t[5] = (__bf16)pf01[mi].y;
                t[6] = (__bf16)pf01[mi].z; t[7] = (__bf16)pf01[mi].w;
                dstFrag[mi] = t;
            }
        }
    };
    auto commit1 = [&](bf16x8* dstFrag) {
        if (BF16A) {
#pragma unroll
            for (int mi = 0; mi < 4; ++mi) {
                union { uint4 u; bf16x8 h; } t; t.u = pa1[mi];
                dstFrag[mi] = t.h;
            }
        } else {
#pragma unroll
            for (int mi = 0; mi < 4; ++mi) {
                bf16x8 t;
                t[0] = (__bf16)pf10[mi].x; t[1] = (__bf16)pf10[mi].y;
                t[2] = (__bf16)pf10[mi].z; t[3] = (__bf16)pf10[mi].w;
                t[4] = (__bf16)pf11[mi].x; t[5] = (__bf16)pf11[mi].y;
                t[6] = (__bf16)pf11[mi].z; t[7] = (__bf16)pf11[mi].w;
                dstFrag[mi] = t;
            }
        }
    };

    // ---- prologue: issue A(0,1); stage B(0,1) into pair 0; barrier drains loads ----
    issue0(0);                // step 0 (row0,wb0)
    issue1(WW);               // step 1 (row1,wb0)
    stageB(0, 0, 0);
    stageB(1, 0, TILE_E);
    __syncthreads();          // pair 0 ready; pa loads complete (barrier drain)

    // ---- main loop: 24 rounds x 2 steps, 1 barrier/round ----
    // entry invariant: pa = A(2r,2r+1) COMPLETE; (nr,nwb) = (row,wb) of step 2r+2.
    int nr = 2, nwb = 0;
    int rdE = 0;
    bf16x8 fa0[4], fa1[4];
#pragma unroll 1
    for (int r = 0; r < 24; ++r) {
        // 1. B fragments for steps 2r, 2r+1 (issue ds_reads early)
        bf16x8 fb0[4], fb1[4];
#pragma unroll
        for (int i = 0; i < 4; ++i) {
            fb0[i] = *(const bf16x8*)(&Bs[rdE + br_off + i * 16 * LDS_STRIDE]);
            fb1[i] = *(const bf16x8*)(&Bs[rdE + TILE_E + br_off + i * 16 * LDS_STRIDE]);
        }

        // 2. commit pa -> fa (loads already complete: prev barrier drained vmcnt)
        commit0(fa0);
        commit1(fa1);

        // stage coords: t0 = step 2r+2, t1 = step 2r+3
        const int t0r = nr, t0b = nwb;
        int t1r = t0r + 1, t1b = t0b;
        if (t1r == ROWS_PER_CHUNK) { t1r = 0; ++t1b; }
        // advance counters to step 2r+4
        nr = t1r + 1; nwb = t1b;
        if (nr == ROWS_PER_CHUNK) { nr = 0; ++nwb; }

        // 3. issue A for NEXT round (steps 2r+2, 2r+3) at round TOP -- covered by
        //    stageB x2 + 32 MFMAs before the end-of-round barrier drain (R7 lesson).
        issue0(t0r * WW + t0b * 32);                       // step 2r+2 <= 48 always
        if (r <= 22) issue1(t1r * WW + t1b * 32);          // step 2r+3 <= 48 iff r<=22

        // 4. B-gen for steps 2r+2, 2r+3 into write pair (VALU; covers load latency)
        const int wrE = rdE ^ PAIR_E;
        stageB(t0r, t0b, wrE);
        if (r <= 22) stageB(t1r, t1b, wrE + TILE_E);

        // 5. 32 MFMAs consuming THIS round's fa
#pragma unroll
        for (int mi = 0; mi < 4; ++mi)
#pragma unroll
            for (int ni = 0; ni < 4; ++ni)
                acc[mi][ni] = __builtin_amdgcn_mfma_f32_16x16x32_bf16(
                    fa0[mi], fb0[ni], acc[mi][ni], 0, 0, 0);
#pragma unroll
        for (int mi = 0; mi < 4; ++mi)
#pragma unroll
            for (int ni = 0; ni < 4; ++ni)
                acc[mi][ni] = __builtin_amdgcn_mfma_f32_16x16x32_bf16(
                    fa1[mi], fb1[ni], acc[mi][ni], 0, 0, 0);

        __syncthreads();
        rdE ^= PAIR_E;
    }

    // ---- tail: step 48. rdE==0; B48 staged at r=23 into tile 0; pa0 = A48 complete ----
    {
        bf16x8 fbL[4];
#pragma unroll
        for (int i = 0; i < 4; ++i)
            fbL[i] = *(const bf16x8*)(&Bs[rdE + br_off + i * 16 * LDS_STRIDE]);
        commit0(fa0);
#pragma unroll
        for (int mi = 0; mi < 4; ++mi)
#pragma unroll
            for (int ni = 0; ni < 4; ++ni)
                acc[mi][ni] = __builtin_amdgcn_mfma_f32_16x16x32_bf16(
                    fa0[mi], fbL[ni], acc[mi][ni], 0, 0, 0);
    }

    // ---- epilogue: C/D layout col=lane&15, row=(lane>>4)*4+reg ----
    const int orow = (lane >> 4) * 4;
    float* base = PARTIAL ? (dst + (size_t)z * BB * CC) : dst;
#pragma unroll
    for (int mi = 0; mi < 4; ++mi) {
        int m = wm + mi * 16 + orow;
#pragma unroll
        for (int ni = 0; ni < 4; ++ni) {
            int cc = c0 + ni * 16 + fl;
#pragma unroll
            for (int v = 0; v < 4; ++v) {
                if (PARTIAL)
                    base[(size_t)(m + v) * CC + cc] = acc[mi][ni][v];
                else
                    atomicAdd(base + (size_t)(m + v) * CC + cc, acc[mi][ni][v]);
            }
        }
    }
}

extern "C" void kernel_launch(void* const* d_in, const int* in_sizes, int n_in,
                              void* d_out, int out_size, void* d_ws, size_t ws_size,
                              hipStream_t stream) {
    const float* x   = (const float*)d_in[0];
    const float* pos = (const float*)d_in[1];
    const float* sg  = (const float*)d_in[2];
    const float* cw  = (const float*)d_in[3];
    const float* xs  = (const float*)d_in[4];
    const float* ys  = (const float*)d_in[5];
    float* out = (float*)d_out;

    dim3 grid(16 * KCHUNKS);       // 512 blocks (flattened, XCD-swizzled in-kernel)
    const size_t nx   = (size_t)BB * KK;
    const size_t XB   = nx * sizeof(__hip_bfloat16);            // 25.7 MB
    const size_t PART = (size_t)KCHUNKS * BB * CC * 4;          // 33.6 MB
    const int n8 = (int)(nx / 8);

    if (ws_size >= XB + PART) {
        __hip_bfloat16* xb = (__hip_bfloat16*)d_ws;
        float* part = (float*)((char*)d_ws + XB);
        cvt_bf16_kernel<<<(n8 + 255) / 256, 256, 0, stream>>>(x, xb, n8);
        blob_gemm_kernel<true, true><<<grid, 256, 0, stream>>>(xb, pos, sg, cw, xs, ys, part);
        reduce_kernel<<<BB * CC / 4 / 256, 256, 0, stream>>>(part, out);
    } else if (ws_size >= PART) {
        float* part = (float*)d_ws;
        blob_gemm_kernel<false, true><<<grid, 256, 0, stream>>>(x, pos, sg, cw, xs, ys, part);
        reduce_kernel<<<BB * CC / 4 / 256, 256, 0, stream>>>(part, out);
    } else if (ws_size >= XB) {
        __hip_bfloat16* xb = (__hip_bfloat16*)d_ws;
        hipMemsetAsync(out, 0, (size_t)BB * CC * sizeof(float), stream);
        cvt_bf16_kernel<<<(n8 + 255) / 256, 256, 0, stream>>>(x, xb, n8);
        blob_gemm_kernel<true, false><<<grid, 256, 0, stream>>>(xb, pos, sg, cw, xs, ys, out);
    } else {
        hipMemsetAsync(out, 0, (size_t)BB * CC * sizeof(float), stream);
        blob_gemm_kernel<false, false><<<grid, 256, 0, stream>>>(x, pos, sg, cw, xs, ys, out);
    }
}